// Round 2
// baseline (446.542 us; speedup 1.0000x reference)
//
#include <hip/hip_runtime.h>

// Problem: N=4194304 rows x C=16 f32; err=|1-input[i,target[i]]|; per-group(8) mean; |0.5-mean(means)|
#define N_ELEMS 4194304
#define C_DIM 16
#define G_NUM 8
#define ROWS_PER_STAGE 256        // 256 rows x 64B = 16 KB LDS tile
#define NUM_STAGES (N_ELEMS / ROWS_PER_STAGE)   // 16384

// ws layout: [0..7] float sums, [8..15] uint counts (64 B, zeroed via hipMemsetAsync)

__global__ __launch_bounds__(256) void berl_partial(
    const float* __restrict__ input_,
    const int*   __restrict__ target,
    const int*   __restrict__ group,
    float*        __restrict__ g_sums,
    unsigned int* __restrict__ g_counts)
{
    // 256 rows x 16 floats = 16 KB staging tile (each row == one 64B cache line)
    __shared__ float4       s_rows[ROWS_PER_STAGE * 4];
    __shared__ float        s_sums[G_NUM];
    __shared__ unsigned int s_counts[G_NUM];

    const int tid = threadIdx.x;
    if (tid < G_NUM) { s_sums[tid] = 0.0f; s_counts[tid] = 0u; }

    float sums[G_NUM];
    float cnts[G_NUM];
#pragma unroll
    for (int k = 0; k < G_NUM; ++k) { sums[k] = 0.0f; cnts[k] = 0.0f; }

    const float4* __restrict__ in4 = (const float4*)input_;

    for (int s = blockIdx.x; s < NUM_STAGES; s += gridDim.x) {
        const int row0 = s * ROWS_PER_STAGE;
        const int f4_base = row0 * 4;            // 4 float4 per row

        // Coalesced streaming load: 1024 float4 per stage, 4 per thread.
        // Consecutive lanes -> consecutive 16B -> full-line transactions.
#pragma unroll
        for (int q = 0; q < 4; ++q) {
            s_rows[tid + 256 * q] = in4[f4_base + tid + 256 * q];
        }
        __syncthreads();

        // One row per thread: pick the target element from LDS.
        const int t = target[row0 + tid];
        const int g = group[row0 + tid];
        const float v = ((const float*)s_rows)[tid * C_DIM + t];
        const float e = fabsf(1.0f - v);
#pragma unroll
        for (int k = 0; k < G_NUM; ++k) {
            sums[k] += (g == k) ? e : 0.0f;
            cnts[k] += (g == k) ? 1.0f : 0.0f;
        }
        __syncthreads();   // protect LDS tile before next stage's overwrite
    }

    // thread -> block partials (16 LDS atomics/thread)
#pragma unroll
    for (int k = 0; k < G_NUM; ++k) {
        atomicAdd(&s_sums[k], sums[k]);
        atomicAdd(&s_counts[k], (unsigned int)cnts[k]);
    }
    __syncthreads();

    // block -> global (16 atomics/block, 2048 blocks)
    if (tid < G_NUM) {
        atomicAdd(&g_sums[tid], s_sums[tid]);
        atomicAdd(&g_counts[tid], s_counts[tid]);
    }
}

__global__ void berl_final(const float* __restrict__ g_sums,
                           const unsigned int* __restrict__ g_counts,
                           float* __restrict__ out)
{
    if (threadIdx.x == 0 && blockIdx.x == 0) {
        float acc = 0.0f;
#pragma unroll
        for (int g = 0; g < G_NUM; ++g) {
            float c = (float)g_counts[g];
            float m = (c > 0.0f) ? (g_sums[g] / fmaxf(c, 1.0f)) : 0.0f;
            acc += m;
        }
        out[0] = fabsf(0.5f - acc / (float)G_NUM);
    }
}

extern "C" void kernel_launch(void* const* d_in, const int* in_sizes, int n_in,
                              void* d_out, int out_size, void* d_ws, size_t ws_size,
                              hipStream_t stream) {
    const float* input_ = (const float*)d_in[0];
    const int*   target = (const int*)d_in[1];
    const int*   group  = (const int*)d_in[2];
    float* out = (float*)d_out;

    float*        g_sums   = (float*)d_ws;
    unsigned int* g_counts = (unsigned int*)((char*)d_ws + G_NUM * sizeof(float));

    hipMemsetAsync(d_ws, 0, G_NUM * (sizeof(float) + sizeof(unsigned int)), stream);

    dim3 block(256);
    dim3 grid(2048);   // 8 blocks/CU resident (wave-limited), 8 stages/block
    berl_partial<<<grid, block, 0, stream>>>(input_, target, group, g_sums, g_counts);
    berl_final<<<1, 64, 0, stream>>>(g_sums, g_counts, out);
}

// Round 4
// 435.421 us; speedup vs baseline: 1.0255x; 1.0255x over previous
//
#include <hip/hip_runtime.h>

// N=4194304 rows x C=16 f32; err=|1-input[i,target[i]]|; per-group(8) mean; |0.5-mean(means)|
#define N_ELEMS 4194304
#define C_DIM 16
#define G_NUM 8

#define THREADS 256
#define GRID 2048
// total float4 elements in input_: N*C/4 = 16,777,216 = (GRID*THREADS) * 32
#define NF4 (N_ELEMS * (C_DIM / 4))
#define ITERS (NF4 / (GRID * THREADS))   // 32
#define UNROLL 4

// native clang vector type — accepted by __builtin_nontemporal_load
typedef float vfloat4 __attribute__((ext_vector_type(4)));

// ws layout: [0..7] float sums, [8..15] uint counts (64 B, zeroed via hipMemsetAsync)

__device__ __forceinline__ void process_one(vfloat4 v, int j, int t, int g,
                                            float* sums, float* cnts)
{
    const int f  = j & 3;              // which float4 of the row this lane holds
    const int tf = t >> 2;             // which float4 holds the target
    const int c  = t & 3;              // component within that float4
    // component select (only meaningful when f==tf)
    float x = (c == 0) ? v.x : (c == 1) ? v.y : (c == 2) ? v.z : v.w;
    const bool hit = (f == tf);
    const float e   = hit ? fabsf(1.0f - x) : 0.0f;
    const float one = hit ? 1.0f : 0.0f;   // exactly one lane per row counts it
#pragma unroll
    for (int k = 0; k < G_NUM; ++k) {
        const bool m = (g == k);
        sums[k] += m ? e : 0.0f;
        cnts[k] += m ? one : 0.0f;
    }
}

__global__ __launch_bounds__(THREADS) void berl_partial(
    const float* __restrict__ input_,
    const int*   __restrict__ target,
    const int*   __restrict__ group,
    float*        __restrict__ g_sums,
    unsigned int* __restrict__ g_counts)
{
    __shared__ float        s_sums[G_NUM];
    __shared__ unsigned int s_counts[G_NUM];
    const int tid = threadIdx.x;
    if (tid < G_NUM) { s_sums[tid] = 0.0f; s_counts[tid] = 0u; }

    float sums[G_NUM];
    float cnts[G_NUM];
#pragma unroll
    for (int k = 0; k < G_NUM; ++k) { sums[k] = 0.0f; cnts[k] = 0.0f; }

    const vfloat4* __restrict__ in4 = (const vfloat4*)input_;
    const int base   = blockIdx.x * THREADS + tid;
    const int stride = GRID * THREADS;

    // Pure streaming: coalesced float4 loads; each lane contributes only if its
    // quarter-row contains the target element. No barriers, no LDS in hot loop.
#pragma unroll 1
    for (int it = 0; it < ITERS; it += UNROLL) {
        int     j[UNROLL];
        vfloat4 v[UNROLL];
        int     t[UNROLL], g[UNROLL];
#pragma unroll
        for (int u = 0; u < UNROLL; ++u) {
            j[u] = base + (it + u) * stride;
            v[u] = __builtin_nontemporal_load(&in4[j[u]]);   // read-once stream
        }
#pragma unroll
        for (int u = 0; u < UNROLL; ++u) {
            const int r = j[u] >> 2;   // row index (4 lanes share a row)
            t[u] = target[r];
            g[u] = group[r];
        }
#pragma unroll
        for (int u = 0; u < UNROLL; ++u) {
            process_one(v[u], j[u], t[u], g[u], sums, cnts);
        }
    }

    // thread -> block partials
    __syncthreads();   // ensure s_sums/s_counts init visible
#pragma unroll
    for (int k = 0; k < G_NUM; ++k) {
        atomicAdd(&s_sums[k], sums[k]);
        atomicAdd(&s_counts[k], (unsigned int)cnts[k]);
    }
    __syncthreads();

    // block -> global (16 atomics/block, 2048 blocks)
    if (tid < G_NUM) {
        atomicAdd(&g_sums[tid], s_sums[tid]);
        atomicAdd(&g_counts[tid], s_counts[tid]);
    }
}

__global__ void berl_final(const float* __restrict__ g_sums,
                           const unsigned int* __restrict__ g_counts,
                           float* __restrict__ out)
{
    if (threadIdx.x == 0 && blockIdx.x == 0) {
        float acc = 0.0f;
#pragma unroll
        for (int g = 0; g < G_NUM; ++g) {
            float c = (float)g_counts[g];
            float m = (c > 0.0f) ? (g_sums[g] / fmaxf(c, 1.0f)) : 0.0f;
            acc += m;
        }
        out[0] = fabsf(0.5f - acc / (float)G_NUM);
    }
}

extern "C" void kernel_launch(void* const* d_in, const int* in_sizes, int n_in,
                              void* d_out, int out_size, void* d_ws, size_t ws_size,
                              hipStream_t stream) {
    const float* input_ = (const float*)d_in[0];
    const int*   target = (const int*)d_in[1];
    const int*   group  = (const int*)d_in[2];
    float* out = (float*)d_out;

    float*        g_sums   = (float*)d_ws;
    unsigned int* g_counts = (unsigned int*)((char*)d_ws + G_NUM * sizeof(float));

    (void)hipMemsetAsync(d_ws, 0, G_NUM * (sizeof(float) + sizeof(unsigned int)), stream);

    berl_partial<<<dim3(GRID), dim3(THREADS), 0, stream>>>(input_, target, group, g_sums, g_counts);
    berl_final<<<1, 64, 0, stream>>>(g_sums, g_counts, out);
}